// Round 8
// baseline (249.755 us; speedup 1.0000x reference)
//
#include <hip/hip_runtime.h>

#define BB 4
#define NN 512
#define HH 128
#define EHH 128
#define JC 16

typedef short short8 __attribute__((ext_vector_type(8)));
typedef float f32x4 __attribute__((ext_vector_type(4)));
typedef int   int4v __attribute__((ext_vector_type(4)));

__device__ __forceinline__ float fsilu(float x){
    float e = __expf(-x);
    return x * __builtin_amdgcn_rcpf(1.0f + e);
}

__device__ __forceinline__ unsigned int cvt_pk_bf16(float lo, float hi){
    unsigned int r;
    asm("v_cvt_pk_bf16_f32 %0, %1, %2" : "=v"(r) : "v"(lo), "v"(hi));
    return r;
}

__device__ __forceinline__ unsigned short f2bf(float f){
    return (unsigned short)(cvt_pk_bf16(f, 0.f) & 0xffffu);
}

// packed fp8 e4m3 convert: byte0 = cvt(lo), byte1 = cvt(hi)
__device__ __forceinline__ unsigned int cvt_pk_fp8(float lo, float hi){
    unsigned int r;
    asm("v_cvt_pk_fp8_f32 %0, %1, %2" : "=v"(r) : "v"(lo), "v"(hi));
    return r;
}

// ---------------- prep: projections + weight conversions ------------------
__global__ __launch_bounds__(256) void k_prep(
    const float* __restrict__ h,
    const float* __restrict__ We1, const float* __restrict__ be1,
    const float* __restrict__ We2, const float* __restrict__ Wc1,
    float* __restrict__ hi_e, unsigned short* __restrict__ hj_eb,
    unsigned short* __restrict__ We2T, unsigned char* __restrict__ Wc1F8)
{
    const int tid = threadIdx.x;
    if (blockIdx.x < BB*NN/8) {
        __shared__ float hrows[8][HH];
        const int row0 = blockIdx.x * 8;
        #pragma unroll
        for (int t = tid; t < 8*HH; t += 256)
            hrows[t >> 7][t & 127] = h[row0*HH + t];
        __syncthreads();
        const int col  = tid & 127;
        const int half = tid >> 7;
        float acc[8] = {0.f,0.f,0.f,0.f,0.f,0.f,0.f,0.f};
        #pragma unroll 4
        for (int k = 0; k < HH; ++k){
            float w = We1[(half*HH + k)*EHH + col];
            #pragma unroll
            for (int r = 0; r < 8; ++r) acc[r] += hrows[r][k] * w;
        }
        if (half == 0){
            const float bb = be1[col];
            #pragma unroll
            for (int r = 0; r < 8; ++r)
                hi_e[(row0 + r)*EHH + col] = acc[r] + bb;
        } else {
            #pragma unroll
            for (int r = 0; r < 8; ++r)
                hj_eb[(row0 + r)*EHH + col] = f2bf(acc[r]);
        }
    } else {
        const int bid = blockIdx.x - BB*NN/8;   // 0..15
        for (int t = bid*256 + tid; t < 128*128; t += 16*256){
            int o = t >> 7, kk = t & 127;
            We2T[t] = f2bf(We2[kk*HH + o]);          // We2T[col][k]
        }
        for (int idx = bid*256 + tid; idx < 8192; idx += 16*256){
            int o = idx >> 6, kp = idx & 63;
            int k = 2*kp;
            unsigned int pk = cvt_pk_fp8(Wc1[k*EHH + o] * 16.f,
                                         Wc1[(k+1)*EHH + o] * 16.f);
            *(unsigned short*)&Wc1F8[o*EHH + k] = (unsigned short)(pk & 0xffffu);
        }
    }
}

// ---------------- fused edge kernel: wave-independent, barrier-free -------
// grid 512 = B*N/4. 256 threads = 4 waves, wave w owns i = blk*4 + w.
__global__ __launch_bounds__(256, 2) void k_edge(
    const float* __restrict__ x,
    const float* __restrict__ hi_e,
    const unsigned short* __restrict__ hj_eb,
    const unsigned short* __restrict__ We2T,
    const unsigned char* __restrict__ Wc1F8,
    const float* __restrict__ We1,
    const float* __restrict__ be2,
    const float* __restrict__ bc1,
    const float* __restrict__ wc2,
    const float* __restrict__ bc2p,
    const int* __restrict__ radius,
    float* __restrict__ aggb, float* __restrict__ xout)
{
    __shared__ unsigned short We2T_s[128][136];   // bf16 [col][k], 272B stride (16B mult)
    __shared__ unsigned char  Wc1F8_s[128][144];  // fp8  [col][k], 144B stride (16B mult)
    __shared__ unsigned short jlist[4][NN];       // per-wave neighbor list
    __shared__ unsigned char  mA8[4][JC][136];    // per-wave m tile (fp8 x8)

    const int tid  = threadIdx.x;
    const int lane = tid & 63;
    const int wave = tid >> 6;
    const int l15  = lane & 15;
    const int g    = lane >> 4;

    const int b    = blockIdx.x >> 7;
    const int i    = (blockIdx.x & 127) * 4 + wave;
    const int base = b * NN;

    // ---- stage weights into LDS (the only cross-wave phase) --------------
    for (int t = tid; t < 128*16; t += 256){
        int row = t >> 4, seg = t & 15;
        *(short8*)&We2T_s[row][seg*8] = *(const short8*)&We2T[row*EHH + seg*8];
    }
    for (int t = tid; t < 128*8; t += 256){
        int row = t >> 3, seg = t & 7;
        *(int4v*)&Wc1F8_s[row][seg*16] = *(const int4v*)&Wc1F8[row*EHH + seg*16];
    }

    // ---- per-lane persistent registers -----------------------------------
    f32x4 hiA[4], hiB[4], w3A[4], w3B[4];
    #pragma unroll
    for (int ks = 0; ks < 4; ++ks){
        hiA[ks] = *(const f32x4*)&hi_e[(base+i)*EHH + ks*32 + g*8];
        hiB[ks] = *(const f32x4*)&hi_e[(base+i)*EHH + ks*32 + g*8 + 4];
        w3A[ks] = *(const f32x4*)&We1[2*HH*EHH + ks*32 + g*8];
        w3B[ks] = *(const f32x4*)&We1[2*HH*EHH + ks*32 + g*8 + 4];
    }
    float be2r[8], bc1r[8], wc2r[8];
    #pragma unroll
    for (int nt = 0; nt < 8; ++nt){
        const int col = nt*16 + l15;
        be2r[nt] = be2[col];
        bc1r[nt] = bc1[col];
        wc2r[nt] = wc2[col];
    }
    const float xi0 = x[(base+i)*3+0];
    const float xi1 = x[(base+i)*3+1];
    const float xi2 = x[(base+i)*3+2];
    const int   rad = radius[0];
    const float r2  = (float)(rad*rad);
    const float bc2v = bc2p[0];

    // ---- per-wave neighbor compaction ------------------------------------
    int cnt = 0;
    #pragma unroll 1
    for (int t = 0; t < NN/64; ++t){
        const int j = t*64 + lane;
        float xj0 = x[(base+j)*3+0];
        float xj1 = x[(base+j)*3+1];
        float xj2 = x[(base+j)*3+2];
        float d0 = xi0-xj0, d1 = xi1-xj1, d2c = xi2-xj2;
        float d2v = d0*d0 + d1*d1 + d2c*d2c;
        bool pass = (d2v < r2) && (j != i);
        unsigned long long bal = __ballot(pass);
        int pos = __popcll(bal & ((1ull << lane) - 1ull));
        if (pass) jlist[wave][cnt + pos] = (unsigned short)j;
        cnt += __popcll(bal);
    }

    __syncthreads();   // weights staged; jlist per-wave (no cross-wave dep)

    const int nch = (cnt + JC - 1) / JC;

    float agg[8] = {0.f,0.f,0.f,0.f,0.f,0.f,0.f,0.f};
    float cx = 0.f, cy = 0.f, cz = 0.f;

    // prologue: prefetch chunk 0 (lane's own row = l15)
    short8 hjp[4];
    float xjp0 = 0.f, xjp1 = 0.f, xjp2 = 0.f;
    if (nch > 0){
        int idx = l15 < cnt ? l15 : cnt-1;
        int jn = jlist[wave][idx];
        #pragma unroll
        for (int ks = 0; ks < 4; ++ks)
            hjp[ks] = *(const short8*)&hj_eb[(base+jn)*EHH + ks*32 + g*8];
        xjp0 = x[(base+jn)*3+0];
        xjp1 = x[(base+jn)*3+1];
        xjp2 = x[(base+jn)*3+2];
    }

    #pragma unroll 1
    for (int c = 0; c < nch; ++c){
        // -------- phase A: A-fragment built fully in registers ------------
        float d0 = xi0 - xjp0;
        float d1 = xi1 - xjp1;
        float d2c = xi2 - xjp2;
        float d2v = d0*d0 + d1*d1 + d2c*d2c;
        short8 a1[4];
        #pragma unroll
        for (int ks = 0; ks < 4; ++ks){
            short8 hj8 = hjp[ks];
            float p[8];
            #pragma unroll
            for (int e = 0; e < 4; ++e){
                float hv0 = __uint_as_float(((unsigned int)(unsigned short)hj8[e]) << 16);
                float hv1 = __uint_as_float(((unsigned int)(unsigned short)hj8[e+4]) << 16);
                p[e]   = fsilu(hiA[ks][e] + hv0 + d2v*w3A[ks][e]);
                p[e+4] = fsilu(hiB[ks][e] + hv1 + d2v*w3B[ks][e]);
            }
            short8 outv;
            ((unsigned int*)&outv)[0] = cvt_pk_bf16(p[0], p[1]);
            ((unsigned int*)&outv)[1] = cvt_pk_bf16(p[2], p[3]);
            ((unsigned int*)&outv)[2] = cvt_pk_bf16(p[4], p[5]);
            ((unsigned int*)&outv)[3] = cvt_pk_bf16(p[6], p[7]);
            a1[ks] = outv;
        }
        // prefetch chunk c+1 (hides under GEMM1..epi2)
        if (c + 1 < nch){
            int idx = (c+1)*JC + l15;
            idx = idx < cnt ? idx : cnt-1;
            int jn = jlist[wave][idx];
            #pragma unroll
            for (int ks = 0; ks < 4; ++ks)
                hjp[ks] = *(const short8*)&hj_eb[(base+jn)*EHH + ks*32 + g*8];
            xjp0 = x[(base+jn)*3+0];
            xjp1 = x[(base+jn)*3+1];
            xjp2 = x[(base+jn)*3+2];
        }

        // -------- GEMM1: m_pre[16x128] = a1 @ We2 (B from LDS) ------------
        f32x4 acc1[8];
        #pragma unroll
        for (int nt = 0; nt < 8; ++nt) acc1[nt] = (f32x4){0.f,0.f,0.f,0.f};
        #pragma unroll
        for (int ks = 0; ks < 4; ++ks){
            #pragma unroll
            for (int nt = 0; nt < 8; ++nt){
                short8 bf = *(const short8*)&We2T_s[nt*16 + l15][ks*32 + g*8];
                acc1[nt] = __builtin_amdgcn_mfma_f32_16x16x32_bf16(
                    a1[ks], bf, acc1[nt], 0, 0, 0);
            }
        }

        // -------- epi1: m = silu(.+be2)*mask; agg += m; mA8 = fp8(m*8) ----
        float mfr[4];
        #pragma unroll
        for (int rg = 0; rg < 4; ++rg)
            mfr[rg] = (c*JC + 4*g + rg < cnt) ? 1.f : 0.f;
        #pragma unroll
        for (int nt = 0; nt < 8; ++nt){
            f32x4 v = acc1[nt];
            #pragma unroll
            for (int rg = 0; rg < 4; ++rg){
                float m = fsilu(v[rg] + be2r[nt]) * mfr[rg];
                agg[nt] += m;
                mA8[wave][4*g + rg][nt*16 + l15] =
                    (unsigned char)(cvt_pk_fp8(m * 8.f, 0.f) & 0xffu);
            }
        }

        // -------- GEMM2 (fp8): gate_pre = m @ Wc1 (within-wave LDS) -------
        long a8[4];
        #pragma unroll
        for (int ks = 0; ks < 4; ++ks)
            a8[ks] = *(const long*)&mA8[wave][l15][ks*32 + g*8];
        f32x4 acc2[8];
        #pragma unroll
        for (int nt = 0; nt < 8; ++nt) acc2[nt] = (f32x4){0.f,0.f,0.f,0.f};
        #pragma unroll
        for (int ks = 0; ks < 4; ++ks){
            #pragma unroll
            for (int nt = 0; nt < 8; ++nt){
                long bf8 = *(const long*)&Wc1F8_s[nt*16 + l15][ks*32 + g*8];
                acc2[nt] = __builtin_amdgcn_mfma_f32_16x16x32_fp8_fp8(
                    a8[ks], bf8, acc2[nt], 0, 0, 0);
            }
        }

        // -------- epi2: gate + coord accumulation -------------------------
        float gp[4] = {0.f, 0.f, 0.f, 0.f};
        #pragma unroll
        for (int nt = 0; nt < 8; ++nt){
            f32x4 v = acc2[nt];
            #pragma unroll
            for (int rg = 0; rg < 4; ++rg)
                gp[rg] += fsilu(v[rg]*(1.f/128.f) + bc1r[nt]) * wc2r[nt];
        }
        #pragma unroll
        for (int rg = 0; rg < 4; ++rg){
            float t = gp[rg];
            t += __shfl_xor(t, 1); t += __shfl_xor(t, 2);
            t += __shfl_xor(t, 4); t += __shfl_xor(t, 8);
            float gv = (t + bc2v) * mfr[rg];
            const int row = 4*g + rg;
            float dx0 = __shfl(d0, row);
            float dx1 = __shfl(d1, row);
            float dx2 = __shfl(d2c, row);
            if (l15 == 0){
                cx += dx0*gv; cy += dx1*gv; cz += dx2*gv;
            }
        }
    }

    // -------- agg write (wave-private row) --------------------------------
    #pragma unroll
    for (int nt = 0; nt < 8; ++nt){
        float t = agg[nt];
        t += __shfl_xor(t, 16); t += __shfl_xor(t, 32);
        agg[nt] = t;
    }
    if (lane < 16){
        #pragma unroll
        for (int nt = 0; nt < 8; ++nt)
            aggb[(base + i)*HH + nt*16 + lane] = agg[nt];
    }

    // -------- x write (wave-private row) ----------------------------------
    cx += __shfl_xor(cx, 16); cx += __shfl_xor(cx, 32);
    cy += __shfl_xor(cy, 16); cy += __shfl_xor(cy, 32);
    cz += __shfl_xor(cz, 16); cz += __shfl_xor(cz, 32);
    if (lane == 0){
        float inv = 1.0f / (float)(cnt > 0 ? cnt : 1);
        xout[(base+i)*3 + 0] = xi0 + cx*inv;
        xout[(base+i)*3 + 1] = xi1 + cy*inv;
        xout[(base+i)*3 + 2] = xi2 + cz*inv;
    }
}

// ---------------- node MLP: h_new = h + MLP(concat(h, agg)) ---------------
__global__ __launch_bounds__(128) void k_node(
    const float* __restrict__ h, const float* __restrict__ aggb,
    const float* __restrict__ Wn1, const float* __restrict__ bn1,
    const float* __restrict__ Wn2, const float* __restrict__ bn2,
    float* __restrict__ hout)
{
    __shared__ float hcat[8][260];
    __shared__ float t1[8][132];
    const int tid = threadIdx.x;
    const int row0 = blockIdx.x * 8;
    #pragma unroll
    for (int r = 0; r < 8; ++r){
        hcat[r][tid]      = h[(row0 + r)*HH + tid];
        hcat[r][HH + tid] = aggb[(row0 + r)*HH + tid];
    }
    __syncthreads();
    float acc[8] = {0.f,0.f,0.f,0.f,0.f,0.f,0.f,0.f};
    #pragma unroll 4
    for (int k = 0; k < 2*HH; ++k){
        float w = Wn1[k*EHH + tid];
        #pragma unroll
        for (int r = 0; r < 8; ++r) acc[r] += hcat[r][k] * w;
    }
    const float bn1v = bn1[tid];
    #pragma unroll
    for (int r = 0; r < 8; ++r) t1[r][tid] = fsilu(acc[r] + bn1v);
    __syncthreads();
    float acc2[8] = {0.f,0.f,0.f,0.f,0.f,0.f,0.f,0.f};
    #pragma unroll 4
    for (int e = 0; e < EHH; ++e){
        float w = Wn2[e*HH + tid];
        #pragma unroll
        for (int r = 0; r < 8; ++r) acc2[r] += t1[r][e] * w;
    }
    const float bn2v = bn2[tid];
    #pragma unroll
    for (int r = 0; r < 8; ++r)
        hout[(row0 + r)*HH + tid] = hcat[r][tid] + acc2[r] + bn2v;
}

extern "C" void kernel_launch(void* const* d_in, const int* in_sizes, int n_in,
                              void* d_out, int out_size, void* d_ws, size_t ws_size,
                              hipStream_t stream) {
    const float* h   = (const float*)d_in[0];
    const float* x   = (const float*)d_in[1];
    const float* We1 = (const float*)d_in[2];
    const float* be1 = (const float*)d_in[3];
    const float* We2 = (const float*)d_in[4];
    const float* be2 = (const float*)d_in[5];
    const float* Wc1 = (const float*)d_in[6];
    const float* bc1 = (const float*)d_in[7];
    const float* Wc2 = (const float*)d_in[8];
    const float* bc2 = (const float*)d_in[9];
    const float* Wn1 = (const float*)d_in[10];
    const float* bn1 = (const float*)d_in[11];
    const float* Wn2 = (const float*)d_in[12];
    const float* bn2 = (const float*)d_in[13];
    const int* radius = (const int*)d_in[14];

    float* out_h = (float*)d_out;
    float* out_x = out_h + BB*NN*HH;

    char* ws = (char*)d_ws;
    float*          hi_e  = (float*)ws;                              // 1 MB
    unsigned short* hj_eb = (unsigned short*)(ws + (1u<<20));        // 512 KB
    unsigned short* We2T  = (unsigned short*)(ws + (1u<<20) + (512u<<10));   // 32 KB
    unsigned char*  Wc1F8 = (unsigned char*)(ws + (1u<<20) + (544u<<10));    // 16 KB
    float*          aggb  = (float*)(ws + (1u<<20) + (560u<<10));    // 1 MB

    k_prep<<<BB*NN/8 + 16, 256, 0, stream>>>(h, We1, be1, We2, Wc1,
                                             hi_e, hj_eb, We2T, Wc1F8);
    k_edge<<<BB*NN/4, 256, 0, stream>>>(x, hi_e, hj_eb, We2T, Wc1F8,
                                        We1, be2, bc1, Wc2, bc2, radius,
                                        aggb, out_x);
    k_node<<<BB*NN/8, 128, 0, stream>>>(h, aggb, Wn1, bn1, Wn2, bn2, out_h);
}

// Round 10
// 210.952 us; speedup vs baseline: 1.1839x; 1.1839x over previous
//
#include <hip/hip_runtime.h>

#define BB 4
#define NN 512
#define HH 128
#define EHH 128
#define JB 64

typedef short short8 __attribute__((ext_vector_type(8)));
typedef float f32x4 __attribute__((ext_vector_type(4)));

__device__ __forceinline__ float fsilu(float x){
    float e = __expf(-x);
    return x * __builtin_amdgcn_rcpf(1.0f + e);
}

__device__ __forceinline__ unsigned int cvt_pk_bf16(float lo, float hi){
    unsigned int r;
    asm("v_cvt_pk_bf16_f32 %0, %1, %2" : "=v"(r) : "v"(lo), "v"(hi));
    return r;
}

__device__ __forceinline__ unsigned short f2bf(float f){
    return (unsigned short)(cvt_pk_bf16(f, 0.f) & 0xffffu);
}

// packed fp8 e4m3 convert: byte0 = cvt(lo), byte1 = cvt(hi)
__device__ __forceinline__ unsigned int cvt_pk_fp8(float lo, float hi){
    unsigned int r;
    asm("v_cvt_pk_fp8_f32 %0, %1, %2" : "=v"(r) : "v"(lo), "v"(hi));
    return r;
}

// ---------------- prep: projections (4 rows/block) + weight conversions ---
// grid: 512 row-blocks + 16 weight-conversion blocks
__global__ __launch_bounds__(256) void k_prep(
    const float* __restrict__ h,
    const float* __restrict__ We1, const float* __restrict__ be1,
    const float* __restrict__ We2, const float* __restrict__ Wc1,
    float* __restrict__ hi_e, unsigned short* __restrict__ hj_eb,
    unsigned short* __restrict__ We2T, unsigned char* __restrict__ Wc1F8)
{
    const int tid = threadIdx.x;
    if (blockIdx.x < BB*NN/4) {
        __shared__ float hrows[4][HH];
        const int row0 = blockIdx.x * 4;
        for (int t = tid; t < 4*HH; t += 256)
            hrows[t >> 7][t & 127] = h[row0*HH + t];
        __syncthreads();
        const int col  = tid & 127;
        const int half = tid >> 7;           // 0: hi (We1[0:128]), 1: hj (We1[128:256])
        const float* W = We1 + half*HH*EHH + col;
        float a0 = 0.f, a1 = 0.f, a2 = 0.f, a3 = 0.f;
        #pragma unroll 8
        for (int k = 0; k < HH; ++k){
            float w = W[k*EHH];
            a0 += hrows[0][k] * w;
            a1 += hrows[1][k] * w;
            a2 += hrows[2][k] * w;
            a3 += hrows[3][k] * w;
        }
        if (half == 0){
            const float bb = be1[col];
            hi_e[(row0+0)*EHH + col] = a0 + bb;
            hi_e[(row0+1)*EHH + col] = a1 + bb;
            hi_e[(row0+2)*EHH + col] = a2 + bb;
            hi_e[(row0+3)*EHH + col] = a3 + bb;
        } else {
            hj_eb[(row0+0)*EHH + col] = f2bf(a0);
            hj_eb[(row0+1)*EHH + col] = f2bf(a1);
            hj_eb[(row0+2)*EHH + col] = f2bf(a2);
            hj_eb[(row0+3)*EHH + col] = f2bf(a3);
        }
    } else {
        const int bid = blockIdx.x - BB*NN/4;   // 0..15
        for (int t = bid*256 + tid; t < 128*128; t += 16*256){
            int o = t >> 7, kk = t & 127;
            We2T[t] = f2bf(We2[kk*HH + o]);          // We2T[col][k]
        }
        for (int idx = bid*256 + tid; idx < 8192; idx += 16*256){
            int o = idx >> 6, kp = idx & 63;
            int k = 2*kp;
            unsigned int pk = cvt_pk_fp8(Wc1[k*EHH + o] * 16.f,
                                         Wc1[(k+1)*EHH + o] * 16.f);
            *(unsigned short*)&Wc1F8[o*EHH + k] = (unsigned short)(pk & 0xffffu);
        }
    }
}

// ---------------- fused edge kernel (neighbor-compacted, v6) --------------
// grid 2048 = B*N (one i-row per block). 256 threads = 4 waves (wm x wn = 2x2)
__global__ __launch_bounds__(256, 2) void k_edge(
    const float* __restrict__ x,
    const float* __restrict__ hi_e,
    const unsigned short* __restrict__ hj_eb,
    const unsigned short* __restrict__ We2T,
    const unsigned char* __restrict__ Wc1F8,
    const float* __restrict__ We1,
    const float* __restrict__ be2,
    const float* __restrict__ bc1,
    const float* __restrict__ wc2,
    const float* __restrict__ bc2p,
    const int* __restrict__ radius,
    float* __restrict__ aggb, float* __restrict__ xout)
{
    __shared__ unsigned short A1[JB][136];   // silu(pre) tile, bf16, swizzled
    __shared__ unsigned char  mA8[JB][136];  // m tile, fp8 (x8 scale)
    __shared__ float dxs[2][JB][4];          // dx0,dx1,dx2,mask (dbuf)
    __shared__ float his[HH], w3s[HH];
    __shared__ float aggp[2][HH];
    __shared__ float cred[4][3];
    __shared__ unsigned short jseg[4][128];
    __shared__ unsigned short jlist[NN];
    __shared__ int cnts[4];

    const int tid  = threadIdx.x;
    const int lane = tid & 63;
    const int wave = tid >> 6;
    const int l15  = lane & 15;
    const int g    = lane >> 4;
    const int wm   = wave >> 1, wn = wave & 1;

    const int b = blockIdx.x >> 9;
    const int i = blockIdx.x & (NN-1);
    const int base = b*NN;

    if (tid < HH){
        his[tid] = hi_e[(base + i)*EHH + tid];
        w3s[tid] = We1[2*HH*EHH + tid];
    }
    const float xi0 = x[(base+i)*3+0];
    const float xi1 = x[(base+i)*3+1];
    const float xi2 = x[(base+i)*3+2];
    const int   rad = radius[0];
    const float r2  = (float)(rad*rad);
    const float bc2v = bc2p[0];

    // per-lane epilogue constants
    float be2r[4], bc1r[4], wc2r[4];
    #pragma unroll
    for (int nt = 0; nt < 4; ++nt){
        const int col = wn*64 + nt*16 + l15;
        be2r[nt] = be2[col];
        bc1r[nt] = bc1[col];
        wc2r[nt] = wc2[col];
    }

    // persistent B fragments: bW1 bf16 (64 regs), bW2 fp8 (32 regs)
    short8 bW1[4][4];
    long   bW2[4][4];
    #pragma unroll
    for (int nt = 0; nt < 4; ++nt){
        const int col = wn*64 + nt*16 + l15;
        #pragma unroll
        for (int ks = 0; ks < 4; ++ks){
            bW1[nt][ks] = *(const short8*)&We2T[col*EHH + ks*32 + g*8];
            bW2[nt][ks] = *(const long*)&Wc1F8[col*EHH + ks*32 + g*8];
        }
    }

    // -------- neighbor compaction: wave w owns j in [w*128,(w+1)*128) -----
    int wcnt = 0;
    #pragma unroll
    for (int t = 0; t < 2; ++t){
        const int j = wave*128 + t*64 + lane;
        float xj0 = x[(base+j)*3+0];
        float xj1 = x[(base+j)*3+1];
        float xj2 = x[(base+j)*3+2];
        float d0 = xi0-xj0, d1 = xi1-xj1, d2c = xi2-xj2;
        float d2v = d0*d0 + d1*d1 + d2c*d2c;
        bool pass = (d2v < r2) && (j != i);
        unsigned long long bal = __ballot(pass);
        int pos = __popcll(bal & ((1ull << lane) - 1ull));
        if (pass) jseg[wave][wcnt + pos] = (unsigned short)j;
        wcnt += __popcll(bal);
    }
    if (lane == 0) cnts[wave] = wcnt;
    __syncthreads();                         // S1: cnts/his/w3s ready
    const int c0n = cnts[0], c1n = cnts[1], c2n = cnts[2], c3n = cnts[3];
    const int total = c0n + c1n + c2n + c3n;
    const int off = (wave > 0 ? c0n : 0) + (wave > 1 ? c1n : 0) + (wave > 2 ? c2n : 0);
    for (int k2 = lane; k2 < wcnt; k2 += 64)
        jlist[off + k2] = jseg[wave][k2];
    __syncthreads();                         // S2: jlist ready

    const int nch = (total + JB - 1) / JB;

    float agg[4] = {0.f, 0.f, 0.f, 0.f};
    float cx = 0.f, cy = 0.f, cz = 0.f;

    // prologue: prefetch chunk 0
    short8 hjn[4];
    float xjn0 = 0.f, xjn1 = 0.f, xjn2 = 0.f, mfn = 0.f;
    if (nch > 0){
        const int idx = lane;
        const int vld = idx < total;
        const int jn = vld ? jlist[idx] : jlist[total-1];
        mfn = vld ? 1.f : 0.f;
        #pragma unroll
        for (int k = 0; k < 4; ++k)
            hjn[k] = *(const short8*)&hj_eb[(base + jn)*EHH + wave*32 + k*8];
        xjn0 = x[(base+jn)*3+0];
        xjn1 = x[(base+jn)*3+1];
        xjn2 = x[(base+jn)*3+2];
    }

    #pragma unroll 1
    for (int c = 0; c < nch; ++c){
        const int buf = c & 1;
        const int r = lane;

        // -------- phase A: geometry + A1 build (from prefetched regs) ----
        float d0 = xi0 - xjn0;
        float d1 = xi1 - xjn1;
        float d2c = xi2 - xjn2;
        float d2v = d0*d0 + d1*d1 + d2c*d2c;
        float mf = mfn;
        if (wave == 0){
            dxs[buf][r][0] = d0; dxs[buf][r][1] = d1;
            dxs[buf][r][2] = d2c; dxs[buf][r][3] = mf;
            float t = mf * bc2v;
            cx += d0*t; cy += d1*t; cz += d2c*t;
        }
        const int sw = ((r>>3)&1)<<3;
        #pragma unroll
        for (int k = 0; k < 4; ++k){
            const int c0 = wave*32 + k*8;
            short8 hj8 = hjn[k];
            f32x4 hiA = *(const f32x4*)&his[c0];
            f32x4 hiB = *(const f32x4*)&his[c0+4];
            f32x4 w3A = *(const f32x4*)&w3s[c0];
            f32x4 w3B = *(const f32x4*)&w3s[c0+4];
            float p[8];
            #pragma unroll
            for (int e = 0; e < 4; ++e){
                float hv0 = __uint_as_float(((unsigned int)(unsigned short)hj8[e]) << 16);
                float hv1 = __uint_as_float(((unsigned int)(unsigned short)hj8[e+4]) << 16);
                p[e]   = fsilu(hiA[e] + hv0 + d2v*w3A[e]);
                p[e+4] = fsilu(hiB[e] + hv1 + d2v*w3B[e]);
            }
            short8 outv;
            ((unsigned int*)&outv)[0] = cvt_pk_bf16(p[0], p[1]);
            ((unsigned int*)&outv)[1] = cvt_pk_bf16(p[2], p[3]);
            ((unsigned int*)&outv)[2] = cvt_pk_bf16(p[4], p[5]);
            ((unsigned int*)&outv)[3] = cvt_pk_bf16(p[6], p[7]);
            *(short8*)&A1[r][c0 ^ sw] = outv;
        }
        // prefetch chunk c+1 (lands during GEMM1+GEMM2)
        if (c + 1 < nch){
            const int idx = (c+1)*JB + lane;
            const int vld = idx < total;
            const int jn = vld ? jlist[idx] : jlist[total-1];
            mfn = vld ? 1.f : 0.f;
            #pragma unroll
            for (int k = 0; k < 4; ++k)
                hjn[k] = *(const short8*)&hj_eb[(base + jn)*EHH + wave*32 + k*8];
            xjn0 = x[(base+jn)*3+0];
            xjn1 = x[(base+jn)*3+1];
            xjn2 = x[(base+jn)*3+2];
        }
        __syncthreads();                      // B2: A1/dxs ready

        // -------- GEMM1: m_pre = A1 @ We2 ---------------------------------
        f32x4 acc[2][4];
        #pragma unroll
        for (int mt = 0; mt < 2; ++mt)
            #pragma unroll
            for (int nt = 0; nt < 4; ++nt) acc[mt][nt] = (f32x4){0.f,0.f,0.f,0.f};

        const int swr = ((l15>>3)&1)<<3;
        #pragma unroll
        for (int ks = 0; ks < 4; ++ks){
            short8 afr[2];
            #pragma unroll
            for (int mt = 0; mt < 2; ++mt){
                const int row = wm*32 + mt*16 + l15;
                afr[mt] = *(const short8*)&A1[row][(ks*32 + g*8) ^ swr];
            }
            #pragma unroll
            for (int nt = 0; nt < 4; ++nt)
                #pragma unroll
                for (int mt = 0; mt < 2; ++mt)
                    acc[mt][nt] = __builtin_amdgcn_mfma_f32_16x16x32_bf16(
                        afr[mt], bW1[nt][ks], acc[mt][nt], 0, 0, 0);
        }

        // -------- epi1: m = silu(acc+be2)*mask; agg += m; mA8 = m*8 -------
        #pragma unroll
        for (int mt = 0; mt < 2; ++mt){
            float mfr[4];
            #pragma unroll
            for (int rg = 0; rg < 4; ++rg)
                mfr[rg] = dxs[buf][wm*32 + mt*16 + g*4 + rg][3];
            #pragma unroll
            for (int nt = 0; nt < 4; ++nt){
                const int col = wn*64 + nt*16 + l15;
                f32x4 v = acc[mt][nt];
                #pragma unroll
                for (int rg = 0; rg < 4; ++rg){
                    const int row = wm*32 + mt*16 + g*4 + rg;
                    float m = fsilu(v[rg] + be2r[nt]) * mfr[rg];
                    agg[nt] += m;
                    mA8[row][col] = (unsigned char)(cvt_pk_fp8(m * 8.f, 0.f) & 0xffu);
                }
            }
        }
        __syncthreads();                      // B3: mA8 ready

        // -------- GEMM2 (fp8): g1_pre = m @ Wc1 ---------------------------
        f32x4 acc2[2][4];
        #pragma unroll
        for (int mt = 0; mt < 2; ++mt)
            #pragma unroll
            for (int nt = 0; nt < 4; ++nt) acc2[mt][nt] = (f32x4){0.f,0.f,0.f,0.f};

        #pragma unroll
        for (int ks = 0; ks < 4; ++ks){
            long a8[2];
            #pragma unroll
            for (int mt = 0; mt < 2; ++mt){
                const int row = wm*32 + mt*16 + l15;
                a8[mt] = *(const long*)&mA8[row][ks*32 + g*8];
            }
            #pragma unroll
            for (int nt = 0; nt < 4; ++nt)
                #pragma unroll
                for (int mt = 0; mt < 2; ++mt)
                    acc2[mt][nt] = __builtin_amdgcn_mfma_f32_16x16x32_fp8_fp8(
                        a8[mt], bW2[nt][ks], acc2[mt][nt], 0, 0, 0);
        }

        // -------- epi2: gate partials + per-lane coord accumulation -------
        float gp[2][4];
        #pragma unroll
        for (int mt = 0; mt < 2; ++mt)
            #pragma unroll
            for (int rg = 0; rg < 4; ++rg) gp[mt][rg] = 0.f;
        #pragma unroll
        for (int mt = 0; mt < 2; ++mt)
            #pragma unroll
            for (int nt = 0; nt < 4; ++nt){
                f32x4 v = acc2[mt][nt];
                #pragma unroll
                for (int rg = 0; rg < 4; ++rg)
                    gp[mt][rg] += fsilu(v[rg]*(1.f/128.f) + bc1r[nt]) * wc2r[nt];
            }
        #pragma unroll
        for (int mt = 0; mt < 2; ++mt)
            #pragma unroll
            for (int rg = 0; rg < 4; ++rg){
                const int row = wm*32 + mt*16 + g*4 + rg;
                f32x4 dv = *(const f32x4*)&dxs[buf][row][0];
                float gv = gp[mt][rg] * dv[3];
                cx += dv[0]*gv; cy += dv[1]*gv; cz += dv[2]*gv;
            }
        // no barrier: next phase A writes A1 (reads done pre-B3) and dxs[buf^1]
    }

    // -------- agg write ----------------------------------------------------
    #pragma unroll
    for (int nt = 0; nt < 4; ++nt){
        float t = agg[nt];
        t += __shfl_xor(t, 16); t += __shfl_xor(t, 32);
        agg[nt] = t;
    }
    if (lane < 16){
        #pragma unroll
        for (int nt = 0; nt < 4; ++nt)
            aggp[wm][wn*64 + nt*16 + l15] = agg[nt];
    }

    // -------- coord cross-wave reduce -------------------------------------
    #pragma unroll
    for (int m = 1; m <= 32; m <<= 1){
        cx += __shfl_xor(cx, m);
        cy += __shfl_xor(cy, m);
        cz += __shfl_xor(cz, m);
    }
    if (lane == 0){
        cred[wave][0] = cx; cred[wave][1] = cy; cred[wave][2] = cz;
    }
    __syncthreads();
    if (tid < HH) aggb[(base + i)*HH + tid] = aggp[0][tid] + aggp[1][tid];
    if (tid == 0){
        float sx = cred[0][0] + cred[1][0] + cred[2][0] + cred[3][0];
        float sy = cred[0][1] + cred[1][1] + cred[2][1] + cred[3][1];
        float sz = cred[0][2] + cred[1][2] + cred[2][2] + cred[3][2];
        float inv = 1.0f / (float)(total > 0 ? total : 1);
        xout[(base+i)*3 + 0] = xi0 + sx*inv;
        xout[(base+i)*3 + 1] = xi1 + sy*inv;
        xout[(base+i)*3 + 2] = xi2 + sz*inv;
    }
}

// ---------------- node MLP: h_new = h + MLP(concat(h, agg)) ---------------
// grid 1024 = B*N/2 (2 rows/block). 256 threads = col x half (k-split).
__global__ __launch_bounds__(256) void k_node(
    const float* __restrict__ h, const float* __restrict__ aggb,
    const float* __restrict__ Wn1, const float* __restrict__ bn1,
    const float* __restrict__ Wn2, const float* __restrict__ bn2,
    float* __restrict__ hout)
{
    __shared__ float hin[2][2][132];    // [srchalf][row][col]: h rows / agg rows
    __shared__ float part[2][2][132];   // [half][row][col] partial sums
    __shared__ float t1s[2][132];       // silu layer-1 output
    const int tid  = threadIdx.x;
    const int col  = tid & 127;
    const int half = tid >> 7;
    const int row0 = blockIdx.x * 2;

    if (half == 0){
        hin[0][0][col] = h[(row0+0)*HH + col];
        hin[0][1][col] = h[(row0+1)*HH + col];
    } else {
        hin[1][0][col] = aggb[(row0+0)*HH + col];
        hin[1][1][col] = aggb[(row0+1)*HH + col];
    }
    __syncthreads();

    // layer 1: k-half per thread-half
    float a0 = 0.f, a1 = 0.f;
    {
        const float* W = Wn1 + half*HH*EHH + col;
        #pragma unroll 8
        for (int k = 0; k < HH; ++k){
            float w = W[k*EHH];
            a0 += hin[half][0][k] * w;
            a1 += hin[half][1][k] * w;
        }
    }
    part[half][0][col] = a0;
    part[half][1][col] = a1;
    __syncthreads();
    if (half == 0){
        const float bb = bn1[col];
        t1s[0][col] = fsilu(part[0][0][col] + part[1][0][col] + bb);
        t1s[1][col] = fsilu(part[0][1][col] + part[1][1][col] + bb);
    }
    __syncthreads();

    // layer 2: 64 k's per thread-half
    float b0 = 0.f, b1 = 0.f;
    {
        const float* W = Wn2 + half*64*HH + col;
        #pragma unroll 8
        for (int k = 0; k < 64; ++k){
            float w = W[k*HH];
            b0 += t1s[0][half*64 + k] * w;
            b1 += t1s[1][half*64 + k] * w;
        }
    }
    part[half][0][col] = b0;
    part[half][1][col] = b1;
    __syncthreads();
    if (half == 0){
        const float bb = bn2[col];
        hout[(row0+0)*HH + col] = hin[0][0][col] + part[0][0][col] + part[1][0][col] + bb;
        hout[(row0+1)*HH + col] = hin[0][1][col] + part[0][1][col] + part[1][1][col] + bb;
    }
}

extern "C" void kernel_launch(void* const* d_in, const int* in_sizes, int n_in,
                              void* d_out, int out_size, void* d_ws, size_t ws_size,
                              hipStream_t stream) {
    const float* h   = (const float*)d_in[0];
    const float* x   = (const float*)d_in[1];
    const float* We1 = (const float*)d_in[2];
    const float* be1 = (const float*)d_in[3];
    const float* We2 = (const float*)d_in[4];
    const float* be2 = (const float*)d_in[5];
    const float* Wc1 = (const float*)d_in[6];
    const float* bc1 = (const float*)d_in[7];
    const float* Wc2 = (const float*)d_in[8];
    const float* bc2 = (const float*)d_in[9];
    const float* Wn1 = (const float*)d_in[10];
    const float* bn1 = (const float*)d_in[11];
    const float* Wn2 = (const float*)d_in[12];
    const float* bn2 = (const float*)d_in[13];
    const int* radius = (const int*)d_in[14];

    float* out_h = (float*)d_out;
    float* out_x = out_h + BB*NN*HH;

    char* ws = (char*)d_ws;
    float*          hi_e  = (float*)ws;                              // 1 MB
    unsigned short* hj_eb = (unsigned short*)(ws + (1u<<20));        // 512 KB
    unsigned short* We2T  = (unsigned short*)(ws + (1u<<20) + (512u<<10));   // 32 KB
    unsigned char*  Wc1F8 = (unsigned char*)(ws + (1u<<20) + (544u<<10));    // 16 KB
    float*          aggb  = (float*)(ws + (1u<<20) + (560u<<10));    // 1 MB

    k_prep<<<BB*NN/4 + 16, 256, 0, stream>>>(h, We1, be1, We2, Wc1,
                                             hi_e, hj_eb, We2T, Wc1F8);
    k_edge<<<BB*NN, 256, 0, stream>>>(x, hi_e, hj_eb, We2T, Wc1F8,
                                      We1, be2, bc1, Wc2, bc2, radius,
                                      aggb, out_x);
    k_node<<<BB*NN/2, 256, 0, stream>>>(h, aggb, Wn1, bn1, Wn2, bn2, out_h);
}